// Round 1
// baseline (471.154 us; speedup 1.0000x reference)
//
#include <hip/hip_runtime.h>
#include <hip/hip_bf16.h>
#include <cstdint>

// Problem constants
#define B_ 4
#define S_ 4096
#define D_ 1024
#define DFF_ 4096
#define KSEL_ 2048
#define M_ (B_ * KSEL_)      // 8192 selected rows total
#define NTOK_ (B_ * S_)      // 16384

typedef short bf16x8 __attribute__((ext_vector_type(8)));
typedef float f32x4 __attribute__((ext_vector_type(4)));

__device__ inline unsigned short f2bf(float f) {
    union { float f; unsigned int u; } c; c.f = f;
    unsigned int u = c.u;
    unsigned int r = u + 0x7fffu + ((u >> 16) & 1u);
    return (unsigned short)(r >> 16);
}

// ---------------------------------------------------------------------------
// Transpose + fp32->bf16 convert: src [R][C] f32 -> dst [C][R] bf16
// ---------------------------------------------------------------------------
__global__ __launch_bounds__(256)
void transpose_bf16(const float* __restrict__ src, unsigned short* __restrict__ dst,
                    int R, int C) {
    __shared__ float tile[32][33];
    int c0 = blockIdx.x * 32, r0 = blockIdx.y * 32;
    for (int i = threadIdx.y; i < 32; i += 8)
        tile[i][threadIdx.x] = src[(size_t)(r0 + i) * C + c0 + threadIdx.x];
    __syncthreads();
    for (int i = threadIdx.y; i < 32; i += 8)
        dst[(size_t)(c0 + i) * R + r0 + threadIdx.x] = f2bf(tile[threadIdx.x][i]);
}

// ---------------------------------------------------------------------------
// Router: logits[row] = dot(x[row], Wr); also write xb = bf16(x).
// One wave per row; 4 rows per 256-thread block.
// ---------------------------------------------------------------------------
__global__ __launch_bounds__(256)
void router_kernel(const float* __restrict__ x, const float* __restrict__ Wr,
                   float* __restrict__ logits, unsigned short* __restrict__ xb) {
    int wid = threadIdx.x >> 6, lane = threadIdx.x & 63;
    int row = blockIdx.x * 4 + wid;
    const float* xr = x + (size_t)row * D_;
    unsigned short* xbr = xb + (size_t)row * D_;
    float acc = 0.f;
#pragma unroll
    for (int j = 0; j < 4; j++) {
        int off = j * 256 + lane * 4;
        float4 v = *(const float4*)(xr + off);
        float4 w = *(const float4*)(Wr + off);
        acc += v.x * w.x + v.y * w.y + v.z * w.z + v.w * w.w;
        ushort4 o;
        o.x = f2bf(v.x); o.y = f2bf(v.y); o.z = f2bf(v.z); o.w = f2bf(v.w);
        *(ushort4*)(xbr + off) = o;
    }
#pragma unroll
    for (int s = 32; s; s >>= 1) acc += __shfl_xor(acc, s);
    if (lane == 0) logits[row] = acc;
}

// ---------------------------------------------------------------------------
// Rank: for each token, rank = #{j: l_j > l_i} + #{j: l_j == l_i, j < i};
// selected iff rank < KSEL_. Also accumulate softmax denominator.
// Grid: 16 blocks per batch (256 elements each), block loads all 4096 logits.
// ---------------------------------------------------------------------------
__global__ __launch_bounds__(256)
void rank_kernel(const float* __restrict__ logits, int* __restrict__ flags,
                 float* __restrict__ batch_sum) {
    __shared__ float lg[S_];
    __shared__ float red[256];
    int b = blockIdx.x >> 4, chunk = blockIdx.x & 15;
    const float* L = logits + b * S_;
    for (int j = threadIdx.x; j < S_ / 4; j += 256)
        ((float4*)lg)[j] = ((const float4*)L)[j];
    __syncthreads();
    float mx = -INFINITY;
    for (int j = threadIdx.x; j < S_; j += 256) mx = fmaxf(mx, lg[j]);
    red[threadIdx.x] = mx; __syncthreads();
    for (int s = 128; s; s >>= 1) {
        if (threadIdx.x < s) red[threadIdx.x] = fmaxf(red[threadIdx.x], red[threadIdx.x + s]);
        __syncthreads();
    }
    float m = red[0];
    __syncthreads();   // red is reused below

    int i = chunk * 256 + threadIdx.x;
    float li = lg[i];
    int rank = 0;
    const float4* __restrict__ lg4 = (const float4*)lg;
    for (int jc = 0; jc < S_ / 4; jc++) {
        float4 v = lg4[jc];
        int jb = jc * 4;
        rank += (v.x > li) + (v.y > li) + (v.z > li) + (v.w > li);
        rank += (v.x == li && jb     < i);
        rank += (v.y == li && jb + 1 < i);
        rank += (v.z == li && jb + 2 < i);
        rank += (v.w == li && jb + 3 < i);
    }
    int sel = rank < KSEL_;
    flags[b * S_ + i] = sel;
    float e = sel ? expf(li - m) : 0.f;
    red[threadIdx.x] = e; __syncthreads();
    for (int s = 128; s; s >>= 1) {
        if (threadIdx.x < s) red[threadIdx.x] += red[threadIdx.x + s];
        __syncthreads();
    }
    if (threadIdx.x == 0) atomicAdd(&batch_sum[b], red[0]);
}

// ---------------------------------------------------------------------------
// Compact: prefix-sum flags -> ascending-index selected rows; write
// rowidx[b*2048+pos] = b*4096 + token and rw = softmax weight.
// One block per batch, 256 threads x 16 elements.
// ---------------------------------------------------------------------------
__global__ __launch_bounds__(256)
void compact_kernel(const float* __restrict__ logits, const int* __restrict__ flags,
                    const float* __restrict__ batch_sum,
                    int* __restrict__ rowidx, float* __restrict__ rw) {
    __shared__ float lg[S_];
    __shared__ int f[S_];
    __shared__ int tsum[256];
    __shared__ float red[256];
    int b = blockIdx.x;
    const float* L = logits + b * S_;
    const int* F = flags + b * S_;
    for (int j = threadIdx.x; j < S_ / 4; j += 256) {
        ((float4*)lg)[j] = ((const float4*)L)[j];
        ((int4*)f)[j] = ((const int4*)F)[j];
    }
    __syncthreads();
    float mx = -INFINITY;
    for (int j = threadIdx.x; j < S_; j += 256) mx = fmaxf(mx, lg[j]);
    red[threadIdx.x] = mx; __syncthreads();
    for (int s = 128; s; s >>= 1) {
        if (threadIdx.x < s) red[threadIdx.x] = fmaxf(red[threadIdx.x], red[threadIdx.x + s]);
        __syncthreads();
    }
    float m = red[0];
    float inv = 1.f / batch_sum[b];

    int s0 = 0;
#pragma unroll
    for (int j = 0; j < 16; j++) s0 += f[threadIdx.x * 16 + j];
    tsum[threadIdx.x] = s0; __syncthreads();
    for (int s = 1; s < 256; s <<= 1) {
        int u = (threadIdx.x >= s) ? tsum[threadIdx.x - s] : 0;
        __syncthreads();
        tsum[threadIdx.x] += u;
        __syncthreads();
    }
    int pos = tsum[threadIdx.x] - s0;   // exclusive prefix of selected count
    for (int j = 0; j < 16; j++) {
        int i = threadIdx.x * 16 + j;
        if (f[i]) {
            rowidx[b * KSEL_ + pos] = b * S_ + i;
            rw[b * KSEL_ + pos] = expf(lg[i] - m) * inv;
            pos++;
        }
    }
}

// ---------------------------------------------------------------------------
// Aux loss: BCE-with-logits mean over all 16384 flat logits; targets=1 at the
// flat index set sel.reshape(-1) (values in [0,4096) -> union over batches,
// faithful to the reference's flat-index quirk).
// ---------------------------------------------------------------------------
__global__ __launch_bounds__(256)
void loss_kernel(const float* __restrict__ logits, const int* __restrict__ flags,
                 float* __restrict__ partials) {
    __shared__ float red[256];
    int i = blockIdx.x * 256 + threadIdx.x;
    float l = logits[i];
    float t = 0.f;
    if (i < S_)
        t = (flags[i] | flags[S_ + i] | flags[2 * S_ + i] | flags[3 * S_ + i]) ? 1.f : 0.f;
    float v = fmaxf(l, 0.f) - l * t + log1pf(expf(-fabsf(l)));
    red[threadIdx.x] = v; __syncthreads();
    for (int s = 128; s; s >>= 1) {
        if (threadIdx.x < s) red[threadIdx.x] += red[threadIdx.x + s];
        __syncthreads();
    }
    if (threadIdx.x == 0) partials[blockIdx.x] = red[0];
}

__global__ void loss_final(const float* __restrict__ partials, float* __restrict__ out) {
    float v = partials[threadIdx.x];
#pragma unroll
    for (int s = 32; s; s >>= 1) v += __shfl_xor(v, s);
    if (threadIdx.x == 0) out[0] = v / (float)NTOK_;
}

// ---------------------------------------------------------------------------
// GEMM (m97 structure): C[M=8192][N] = A(bf16, row-gathered for MODE 1) @ B,
// with B given transposed BT[N][K] so both LDS tiles are K-contiguous.
// 128x128 tile, BK=64, 4 waves, each wave a 64x64 sub-tile (4x4 of 16x16x32).
// global_load_lds width 16 with XOR chunk swizzle (source-side) to keep
// fragment ds_read_b128 at 2-way bank aliasing (free).
// MODE 1: H = silu(A@W1), A rows gathered via rowidx, H stored bf16.
// MODE 2: Out[rowidx[m]] = x[rowidx[m]] + (H@W2)[m] * rw[m]  (fp32 scatter).
// ---------------------------------------------------------------------------
template <int MODE>
__global__ __launch_bounds__(256)
void gemm_bt_kernel(const unsigned short* __restrict__ A,
                    const unsigned short* __restrict__ BT,
                    const int* __restrict__ rowidx,
                    const float* __restrict__ rw,
                    const float* __restrict__ x,
                    unsigned short* __restrict__ Hout,
                    float* __restrict__ Out,
                    int K, int N) {
    __shared__ __attribute__((aligned(16))) unsigned short As[128 * 64];
    __shared__ __attribute__((aligned(16))) unsigned short Bs[128 * 64];
    const int tid = threadIdx.x;
    const int w = tid >> 6, lane = tid & 63;
    const int wm = w >> 1, wn = w & 1;
    const int tile_m = blockIdx.y * 128;
    const int tile_n = blockIdx.x * 128;

    // staging: per (issue t, wave w): rows t*32+w*8 .. +8; lane -> row lane>>3,
    // physical 16B chunk lane&7 holding logical chunk (lane&7)^(row&7).
    const int srow = lane >> 3;
    const int sw = (lane & 7) ^ srow;   // logical chunk this lane fetches
    const uint64_t abase = (uint64_t)(uintptr_t)A;
    const uint64_t bbase = (uint64_t)(uintptr_t)BT;
    uint64_t aaddr[4], baddr[4];
#pragma unroll
    for (int t = 0; t < 4; ++t) {
        int r = t * 32 + w * 8 + srow;
        int am = tile_m + r;
        int ar = (MODE == 1) ? rowidx[am] : am;
        aaddr[t] = abase + ((uint64_t)ar * K + (uint64_t)sw * 8) * 2ull;
        int bn = tile_n + r;
        baddr[t] = bbase + ((uint64_t)bn * K + (uint64_t)sw * 8) * 2ull;
    }

    f32x4 acc[4][4];
#pragma unroll
    for (int i = 0; i < 4; i++)
#pragma unroll
        for (int j = 0; j < 4; j++) acc[i][j] = (f32x4){0.f, 0.f, 0.f, 0.f};

    const int lr = lane & 15, quad = lane >> 4;
    const int KI = K >> 6;
    for (int it = 0; it < KI; ++it) {
        const uint64_t koff = (uint64_t)(it * 64) * 2ull;
#pragma unroll
        for (int t = 0; t < 4; ++t) {
            unsigned short* ldsA = &As[(t * 32 + w * 8) * 64];
            unsigned short* ldsB = &Bs[(t * 32 + w * 8) * 64];
            __builtin_amdgcn_global_load_lds(
                (const __attribute__((address_space(1))) unsigned int*)(uintptr_t)(aaddr[t] + koff),
                (__attribute__((address_space(3))) unsigned int*)ldsA, 16, 0, 0);
            __builtin_amdgcn_global_load_lds(
                (const __attribute__((address_space(1))) unsigned int*)(uintptr_t)(baddr[t] + koff),
                (__attribute__((address_space(3))) unsigned int*)ldsB, 16, 0, 0);
        }
        __syncthreads();
#pragma unroll
        for (int ks = 0; ks < 2; ++ks) {
            bf16x8 af[4], bfr[4];
#pragma unroll
            for (int t4 = 0; t4 < 4; ++t4) {
                int row = wm * 64 + t4 * 16 + lr;
                int kc = ks * 4 + quad;
                af[t4] = *(const bf16x8*)((const char*)As + row * 128 + ((kc ^ (lr & 7)) * 16));
                int nr = wn * 64 + t4 * 16 + lr;
                bfr[t4] = *(const bf16x8*)((const char*)Bs + nr * 128 + ((kc ^ (lr & 7)) * 16));
            }
#pragma unroll
            for (int ti = 0; ti < 4; ++ti)
#pragma unroll
                for (int tj = 0; tj < 4; ++tj)
                    acc[ti][tj] = __builtin_amdgcn_mfma_f32_16x16x32_bf16(
                        af[ti], bfr[tj], acc[ti][tj], 0, 0, 0);
        }
        __syncthreads();
    }

    if (MODE == 1) {
#pragma unroll
        for (int ti = 0; ti < 4; ++ti)
#pragma unroll
            for (int r = 0; r < 4; ++r) {
                int m = tile_m + wm * 64 + ti * 16 + quad * 4 + r;
#pragma unroll
                for (int tj = 0; tj < 4; ++tj) {
                    int col = tile_n + wn * 64 + tj * 16 + lr;
                    float v = acc[ti][tj][r];
                    v = v / (1.f + __expf(-v));   // silu
                    Hout[(uint64_t)m * N + col] = f2bf(v);
                }
            }
    } else {
#pragma unroll
        for (int ti = 0; ti < 4; ++ti)
#pragma unroll
            for (int r = 0; r < 4; ++r) {
                int m = tile_m + wm * 64 + ti * 16 + quad * 4 + r;
                int grow = rowidx[m];
                float wgt = rw[m];
                uint64_t rb = (uint64_t)grow * D_;
#pragma unroll
                for (int tj = 0; tj < 4; ++tj) {
                    int col = tile_n + wn * 64 + tj * 16 + lr;
                    Out[rb + col] = x[rb + col] + acc[ti][tj][r] * wgt;
                }
            }
    }
}

// ---------------------------------------------------------------------------
extern "C" void kernel_launch(void* const* d_in, const int* in_sizes, int n_in,
                              void* d_out, int out_size, void* d_ws, size_t ws_size,
                              hipStream_t stream) {
    const float* x  = (const float*)d_in[0];
    // d_in[1] = mask (unused: all-ones in setup, MLP ignores it)
    const float* Wr = (const float*)d_in[2];
    const float* W1 = (const float*)d_in[3];
    const float* W2 = (const float*)d_in[4];
    float* out = (float*)d_out;

    char* ws = (char*)d_ws;
    size_t off = 0;
    auto alloc = [&](size_t bytes) {
        char* p = ws + off;
        off = (off + bytes + 255) & ~(size_t)255;
        return p;
    };
    unsigned short* xb   = (unsigned short*)alloc((size_t)NTOK_ * D_ * 2);  // 33.5 MB
    unsigned short* W1bT = (unsigned short*)alloc((size_t)DFF_ * D_ * 2);   // 8.4 MB
    unsigned short* W2bT = (unsigned short*)alloc((size_t)D_ * DFF_ * 2);   // 8.4 MB
    unsigned short* H    = (unsigned short*)alloc((size_t)M_ * DFF_ * 2);   // 67 MB
    float* logits  = (float*)alloc(NTOK_ * 4);
    int*   flags   = (int*)alloc(NTOK_ * 4);
    int*   rowidx  = (int*)alloc(M_ * 4);
    float* rwp     = (float*)alloc(M_ * 4);
    float* bsum    = (float*)alloc(4 * 4);
    float* partials = (float*)alloc(64 * 4);

    (void)hipMemsetAsync(bsum, 0, 16, stream);
    // hidden_states baseline = x; selected rows overwritten by GEMM2 epilogue
    (void)hipMemcpyAsync(out, x, (size_t)NTOK_ * D_ * 4, hipMemcpyDeviceToDevice, stream);

    transpose_bf16<<<dim3(DFF_ / 32, D_ / 32), dim3(32, 8), 0, stream>>>(W1, W1bT, D_, DFF_);
    transpose_bf16<<<dim3(D_ / 32, DFF_ / 32), dim3(32, 8), 0, stream>>>(W2, W2bT, DFF_, D_);
    router_kernel<<<NTOK_ / 4, 256, 0, stream>>>(x, Wr, logits, xb);
    rank_kernel<<<B_ * 16, 256, 0, stream>>>(logits, flags, bsum);
    compact_kernel<<<B_, 256, 0, stream>>>(logits, flags, bsum, rowidx, rwp);
    loss_kernel<<<NTOK_ / 256, 256, 0, stream>>>(logits, flags, partials);
    loss_final<<<1, 64, 0, stream>>>(partials, out + (size_t)NTOK_ * D_);
    // GEMM1: H[8192][4096] = silu(gather(xb) @ W1)
    gemm_bt_kernel<1><<<dim3(DFF_ / 128, M_ / 128), 256, 0, stream>>>(
        xb, W1bT, rowidx, nullptr, nullptr, H, nullptr, D_, DFF_);
    // GEMM2: out[rowidx[m]] = x[rowidx[m]] + (H @ W2)[m] * rw[m]
    gemm_bt_kernel<2><<<dim3(D_ / 128, M_ / 128), 256, 0, stream>>>(
        H, W2bT, rowidx, rwp, x, nullptr, out, DFF_, D_);
}

// Round 2
// 368.837 us; speedup vs baseline: 1.2774x; 1.2774x over previous
//
#include <hip/hip_runtime.h>
#include <hip/hip_bf16.h>
#include <cstdint>

// Problem constants
#define B_ 4
#define S_ 4096
#define D_ 1024
#define DFF_ 4096
#define KSEL_ 2048
#define M_ (B_ * KSEL_)      // 8192 selected rows total
#define NTOK_ (B_ * S_)      // 16384

typedef short bf16x8 __attribute__((ext_vector_type(8)));
typedef float f32x4 __attribute__((ext_vector_type(4)));

__device__ inline unsigned short f2bf(float f) {
    union { float f; unsigned int u; } c; c.f = f;
    unsigned int u = c.u;
    unsigned int r = u + 0x7fffu + ((u >> 16) & 1u);
    return (unsigned short)(r >> 16);
}

// ---------------------------------------------------------------------------
// Transpose + fp32->bf16 convert: src [R][C] f32 -> dst [C][R] bf16
// ---------------------------------------------------------------------------
__global__ __launch_bounds__(256)
void transpose_bf16(const float* __restrict__ src, unsigned short* __restrict__ dst,
                    int R, int C) {
    __shared__ float tile[32][33];
    int c0 = blockIdx.x * 32, r0 = blockIdx.y * 32;
    for (int i = threadIdx.y; i < 32; i += 8)
        tile[i][threadIdx.x] = src[(size_t)(r0 + i) * C + c0 + threadIdx.x];
    __syncthreads();
    for (int i = threadIdx.y; i < 32; i += 8)
        dst[(size_t)(c0 + i) * R + r0 + threadIdx.x] = f2bf(tile[threadIdx.x][i]);
}

// ---------------------------------------------------------------------------
// Router: logits[row] = dot(x[row], Wr); write xb = bf16(x); write out = x
// (baseline hidden_states copy fused here — x row is already in registers).
// One wave per row; 4 rows per 256-thread block.
// ---------------------------------------------------------------------------
__global__ __launch_bounds__(256)
void router_kernel(const float* __restrict__ x, const float* __restrict__ Wr,
                   float* __restrict__ logits, unsigned short* __restrict__ xb,
                   float* __restrict__ out) {
    int wid = threadIdx.x >> 6, lane = threadIdx.x & 63;
    int row = blockIdx.x * 4 + wid;
    const float* xr = x + (size_t)row * D_;
    unsigned short* xbr = xb + (size_t)row * D_;
    float* outr = out + (size_t)row * D_;
    float acc = 0.f;
#pragma unroll
    for (int j = 0; j < 4; j++) {
        int off = j * 256 + lane * 4;
        float4 v = *(const float4*)(xr + off);
        float4 w = *(const float4*)(Wr + off);
        acc += v.x * w.x + v.y * w.y + v.z * w.z + v.w * w.w;
        *(float4*)(outr + off) = v;
        ushort4 o;
        o.x = f2bf(v.x); o.y = f2bf(v.y); o.z = f2bf(v.z); o.w = f2bf(v.w);
        *(ushort4*)(xbr + off) = o;
    }
#pragma unroll
    for (int s = 32; s; s >>= 1) acc += __shfl_xor(acc, s);
    if (lane == 0) logits[row] = acc;
}

// ---------------------------------------------------------------------------
// Rank (split-j): partial rank over a 512-logit j-chunk, atomicAdd into
// rank[]. rank_i = #{j: l_j > l_i} + #{j: l_j == l_i, j < i}.
// Grid: b(4) x ichunk(16) x jchunk(8) = 512 blocks -> 2 blocks/CU, 8 waves/CU.
// rank[] must be zeroed before launch.
// ---------------------------------------------------------------------------
__global__ __launch_bounds__(256)
void rank_partial_kernel(const float* __restrict__ logits, int* __restrict__ rank) {
    __shared__ float lj[512];
    int b  = blockIdx.x >> 7;
    int ic = (blockIdx.x >> 3) & 15;
    int jc = blockIdx.x & 7;
    const float* L = logits + b * S_;
    for (int t = threadIdx.x; t < 512; t += 256) lj[t] = L[jc * 512 + t];
    __syncthreads();
    int i = ic * 256 + threadIdx.x;
    float li = L[i];
    int jbase = jc * 512;
    int r = 0;
    const float4* __restrict__ lj4 = (const float4*)lj;
#pragma unroll 4
    for (int q = 0; q < 128; q++) {
        float4 v = lj4[q];
        int jb = jbase + q * 4;
        r += (v.x > li) | ((v.x == li) & (jb     < i));
        r += (v.y > li) | ((v.y == li) & (jb + 1 < i));
        r += (v.z > li) | ((v.z == li) & (jb + 2 < i));
        r += (v.w > li) | ((v.w == li) & (jb + 3 < i));
    }
    atomicAdd(&rank[b * S_ + i], r);
}

// ---------------------------------------------------------------------------
// Compact: sel = rank < KSEL_; write flags (for loss); softmax denom over
// selected (local block reduction, no atomics); prefix-sum flags -> ascending
// selected rows; rowidx[b*2048+pos] = b*4096 + token, rw = softmax weight.
// One block per batch, 256 threads x 16 elements.
// ---------------------------------------------------------------------------
__global__ __launch_bounds__(256)
void compact_kernel(const float* __restrict__ logits, const int* __restrict__ rank,
                    int* __restrict__ flags,
                    int* __restrict__ rowidx, float* __restrict__ rw) {
    __shared__ float lg[S_];
    __shared__ int f[S_];
    __shared__ int tsum[256];
    __shared__ float red[256];
    int b = blockIdx.x;
    const float* L = logits + b * S_;
    const int* R = rank + b * S_;
    int* F = flags + b * S_;
    for (int j = threadIdx.x; j < S_ / 4; j += 256) {
        ((float4*)lg)[j] = ((const float4*)L)[j];
        int4 rk = ((const int4*)R)[j];
        int4 fl;
        fl.x = rk.x < KSEL_; fl.y = rk.y < KSEL_;
        fl.z = rk.z < KSEL_; fl.w = rk.w < KSEL_;
        ((int4*)f)[j] = fl;
        ((int4*)F)[j] = fl;
    }
    __syncthreads();
    float mx = -INFINITY;
    for (int j = threadIdx.x; j < S_; j += 256) mx = fmaxf(mx, lg[j]);
    red[threadIdx.x] = mx; __syncthreads();
    for (int s = 128; s; s >>= 1) {
        if (threadIdx.x < s) red[threadIdx.x] = fmaxf(red[threadIdx.x], red[threadIdx.x + s]);
        __syncthreads();
    }
    float m = red[0];
    __syncthreads();

    // softmax denominator over selected
    float esum = 0.f;
    int s0 = 0;
#pragma unroll
    for (int j = 0; j < 16; j++) {
        int i = threadIdx.x * 16 + j;
        s0 += f[i];
        if (f[i]) esum += expf(lg[i] - m);
    }
    red[threadIdx.x] = esum; __syncthreads();
    for (int s = 128; s; s >>= 1) {
        if (threadIdx.x < s) red[threadIdx.x] += red[threadIdx.x + s];
        __syncthreads();
    }
    float inv = 1.f / red[0];

    tsum[threadIdx.x] = s0; __syncthreads();
    for (int s = 1; s < 256; s <<= 1) {
        int u = (threadIdx.x >= s) ? tsum[threadIdx.x - s] : 0;
        __syncthreads();
        tsum[threadIdx.x] += u;
        __syncthreads();
    }
    int pos = tsum[threadIdx.x] - s0;   // exclusive prefix of selected count
    for (int j = 0; j < 16; j++) {
        int i = threadIdx.x * 16 + j;
        if (f[i]) {
            rowidx[b * KSEL_ + pos] = b * S_ + i;
            rw[b * KSEL_ + pos] = expf(lg[i] - m) * inv;
            pos++;
        }
    }
}

// ---------------------------------------------------------------------------
// Aux loss: BCE-with-logits mean over all 16384 flat logits; targets=1 at the
// flat index set sel.reshape(-1) (values in [0,4096) -> union over batches,
// faithful to the reference's flat-index quirk).
// ---------------------------------------------------------------------------
__global__ __launch_bounds__(256)
void loss_kernel(const float* __restrict__ logits, const int* __restrict__ flags,
                 float* __restrict__ partials) {
    __shared__ float red[256];
    int i = blockIdx.x * 256 + threadIdx.x;
    float l = logits[i];
    float t = 0.f;
    if (i < S_)
        t = (flags[i] | flags[S_ + i] | flags[2 * S_ + i] | flags[3 * S_ + i]) ? 1.f : 0.f;
    float v = fmaxf(l, 0.f) - l * t + log1pf(expf(-fabsf(l)));
    red[threadIdx.x] = v; __syncthreads();
    for (int s = 128; s; s >>= 1) {
        if (threadIdx.x < s) red[threadIdx.x] += red[threadIdx.x + s];
        __syncthreads();
    }
    if (threadIdx.x == 0) partials[blockIdx.x] = red[0];
}

__global__ void loss_final(const float* __restrict__ partials, float* __restrict__ out) {
    float v = partials[threadIdx.x];
#pragma unroll
    for (int s = 32; s; s >>= 1) v += __shfl_xor(v, s);
    if (threadIdx.x == 0) out[0] = v / (float)NTOK_;
}

// ---------------------------------------------------------------------------
// GEMM (m97 structure): C[M=8192][N] = A(bf16, row-gathered for MODE 1) @ B,
// with B given transposed BT[N][K] so both LDS tiles are K-contiguous.
// 128x128 tile, BK=64, 4 waves, each wave a 64x64 sub-tile (4x4 of 16x16x32).
// global_load_lds width 16 with XOR chunk swizzle (source-side) to keep
// fragment ds_read_b128 at 2-way bank aliasing (free).
// MODE 1: H = silu(A@W1), A rows gathered via rowidx, H stored bf16.
// MODE 2: Out[rowidx[m]] = x[rowidx[m]] + (H@W2)[m] * rw[m]  (fp32 scatter).
// ---------------------------------------------------------------------------
template <int MODE>
__global__ __launch_bounds__(256)
void gemm_bt_kernel(const unsigned short* __restrict__ A,
                    const unsigned short* __restrict__ BT,
                    const int* __restrict__ rowidx,
                    const float* __restrict__ rw,
                    const float* __restrict__ x,
                    unsigned short* __restrict__ Hout,
                    float* __restrict__ Out,
                    int K, int N) {
    __shared__ __attribute__((aligned(16))) unsigned short As[128 * 64];
    __shared__ __attribute__((aligned(16))) unsigned short Bs[128 * 64];
    const int tid = threadIdx.x;
    const int w = tid >> 6, lane = tid & 63;
    const int wm = w >> 1, wn = w & 1;
    const int tile_m = blockIdx.y * 128;
    const int tile_n = blockIdx.x * 128;

    // staging: per (issue t, wave w): rows t*32+w*8 .. +8; lane -> row lane>>3,
    // physical 16B chunk lane&7 holding logical chunk (lane&7)^(row&7).
    const int srow = lane >> 3;
    const int sw = (lane & 7) ^ srow;   // logical chunk this lane fetches
    const uint64_t abase = (uint64_t)(uintptr_t)A;
    const uint64_t bbase = (uint64_t)(uintptr_t)BT;
    uint64_t aaddr[4], baddr[4];
#pragma unroll
    for (int t = 0; t < 4; ++t) {
        int r = t * 32 + w * 8 + srow;
        int am = tile_m + r;
        int ar = (MODE == 1) ? rowidx[am] : am;
        aaddr[t] = abase + ((uint64_t)ar * K + (uint64_t)sw * 8) * 2ull;
        int bn = tile_n + r;
        baddr[t] = bbase + ((uint64_t)bn * K + (uint64_t)sw * 8) * 2ull;
    }

    f32x4 acc[4][4];
#pragma unroll
    for (int i = 0; i < 4; i++)
#pragma unroll
        for (int j = 0; j < 4; j++) acc[i][j] = (f32x4){0.f, 0.f, 0.f, 0.f};

    const int lr = lane & 15, quad = lane >> 4;
    const int KI = K >> 6;
    for (int it = 0; it < KI; ++it) {
        const uint64_t koff = (uint64_t)(it * 64) * 2ull;
#pragma unroll
        for (int t = 0; t < 4; ++t) {
            unsigned short* ldsA = &As[(t * 32 + w * 8) * 64];
            unsigned short* ldsB = &Bs[(t * 32 + w * 8) * 64];
            __builtin_amdgcn_global_load_lds(
                (const __attribute__((address_space(1))) unsigned int*)(uintptr_t)(aaddr[t] + koff),
                (__attribute__((address_space(3))) unsigned int*)ldsA, 16, 0, 0);
            __builtin_amdgcn_global_load_lds(
                (const __attribute__((address_space(1))) unsigned int*)(uintptr_t)(baddr[t] + koff),
                (__attribute__((address_space(3))) unsigned int*)ldsB, 16, 0, 0);
        }
        __syncthreads();
#pragma unroll
        for (int ks = 0; ks < 2; ++ks) {
            bf16x8 af[4], bfr[4];
#pragma unroll
            for (int t4 = 0; t4 < 4; ++t4) {
                int row = wm * 64 + t4 * 16 + lr;
                int kc = ks * 4 + quad;
                af[t4] = *(const bf16x8*)((const char*)As + row * 128 + ((kc ^ (lr & 7)) * 16));
                int nr = wn * 64 + t4 * 16 + lr;
                bfr[t4] = *(const bf16x8*)((const char*)Bs + nr * 128 + ((kc ^ (lr & 7)) * 16));
            }
#pragma unroll
            for (int ti = 0; ti < 4; ++ti)
#pragma unroll
                for (int tj = 0; tj < 4; ++tj)
                    acc[ti][tj] = __builtin_amdgcn_mfma_f32_16x16x32_bf16(
                        af[ti], bfr[tj], acc[ti][tj], 0, 0, 0);
        }
        __syncthreads();
    }

    if (MODE == 1) {
#pragma unroll
        for (int ti = 0; ti < 4; ++ti)
#pragma unroll
            for (int r = 0; r < 4; ++r) {
                int m = tile_m + wm * 64 + ti * 16 + quad * 4 + r;
#pragma unroll
                for (int tj = 0; tj < 4; ++tj) {
                    int col = tile_n + wn * 64 + tj * 16 + lr;
                    float v = acc[ti][tj][r];
                    v = v / (1.f + __expf(-v));   // silu
                    Hout[(uint64_t)m * N + col] = f2bf(v);
                }
            }
    } else {
#pragma unroll
        for (int ti = 0; ti < 4; ++ti)
#pragma unroll
            for (int r = 0; r < 4; ++r) {
                int m = tile_m + wm * 64 + ti * 16 + quad * 4 + r;
                int grow = rowidx[m];
                float wgt = rw[m];
                uint64_t rb = (uint64_t)grow * D_;
#pragma unroll
                for (int tj = 0; tj < 4; ++tj) {
                    int col = tile_n + wn * 64 + tj * 16 + lr;
                    Out[rb + col] = x[rb + col] + acc[ti][tj][r] * wgt;
                }
            }
    }
}

// ---------------------------------------------------------------------------
extern "C" void kernel_launch(void* const* d_in, const int* in_sizes, int n_in,
                              void* d_out, int out_size, void* d_ws, size_t ws_size,
                              hipStream_t stream) {
    const float* x  = (const float*)d_in[0];
    // d_in[1] = mask (unused: all-ones in setup, MLP ignores it)
    const float* Wr = (const float*)d_in[2];
    const float* W1 = (const float*)d_in[3];
    const float* W2 = (const float*)d_in[4];
    float* out = (float*)d_out;

    char* ws = (char*)d_ws;
    size_t off = 0;
    auto alloc = [&](size_t bytes) {
        char* p = ws + off;
        off = (off + bytes + 255) & ~(size_t)255;
        return p;
    };
    unsigned short* xb   = (unsigned short*)alloc((size_t)NTOK_ * D_ * 2);  // 33.5 MB
    unsigned short* W1bT = (unsigned short*)alloc((size_t)DFF_ * D_ * 2);   // 8.4 MB
    unsigned short* W2bT = (unsigned short*)alloc((size_t)D_ * DFF_ * 2);   // 8.4 MB
    unsigned short* H    = (unsigned short*)alloc((size_t)M_ * DFF_ * 2);   // 67 MB
    float* logits  = (float*)alloc(NTOK_ * 4);
    int*   rank    = (int*)alloc(NTOK_ * 4);
    int*   flags   = (int*)alloc(NTOK_ * 4);
    int*   rowidx  = (int*)alloc(M_ * 4);
    float* rwp     = (float*)alloc(M_ * 4);
    float* partials = (float*)alloc(64 * 4);

    (void)hipMemsetAsync(rank, 0, NTOK_ * 4, stream);

    transpose_bf16<<<dim3(DFF_ / 32, D_ / 32), dim3(32, 8), 0, stream>>>(W1, W1bT, D_, DFF_);
    transpose_bf16<<<dim3(D_ / 32, DFF_ / 32), dim3(32, 8), 0, stream>>>(W2, W2bT, DFF_, D_);
    router_kernel<<<NTOK_ / 4, 256, 0, stream>>>(x, Wr, logits, xb, out);
    rank_partial_kernel<<<512, 256, 0, stream>>>(logits, rank);
    compact_kernel<<<B_, 256, 0, stream>>>(logits, rank, flags, rowidx, rwp);
    loss_kernel<<<NTOK_ / 256, 256, 0, stream>>>(logits, flags, partials);
    loss_final<<<1, 64, 0, stream>>>(partials, out + (size_t)NTOK_ * D_);
    // GEMM1: H[8192][4096] = silu(gather(xb) @ W1)
    gemm_bt_kernel<1><<<dim3(DFF_ / 128, M_ / 128), 256, 0, stream>>>(
        xb, W1bT, rowidx, nullptr, nullptr, H, nullptr, D_, DFF_);
    // GEMM2: out[rowidx[m]] = x[rowidx[m]] + (H @ W2)[m] * rw[m]
    gemm_bt_kernel<2><<<dim3(D_ / 128, M_ / 128), 256, 0, stream>>>(
        H, W2bT, rowidx, rwp, x, nullptr, out, DFF_, D_);
}